// Round 1
// baseline (383.002 us; speedup 1.0000x reference)
//
#include <hip/hip_runtime.h>
#include <stdint.h>

// mean(|x|) > 1.0 over D=128  <=>  sum(|x|) > 128.0
#define THRESH_SUM 128.0f

__device__ __forceinline__ float rl(float v, int lane) {
    return __int_as_float(__builtin_amdgcn_readlane(__float_as_int(v), lane));
}

// Wait lgkmcnt(0) only (vmcnt/expcnt bits all-ones): gfx9/CDNA encoding.
__device__ __forceinline__ void lds_fence_wave() {
    __builtin_amdgcn_wave_barrier();
    __builtin_amdgcn_s_waitcnt(0xc07f);
    __builtin_amdgcn_wave_barrier();
}

__global__ __launch_bounds__(256, 3)
void dyn_mlp_kernel(const float* __restrict__ x,
                    const float* __restrict__ W1, const float* __restrict__ b1,
                    const float* __restrict__ W2, const float* __restrict__ b2,
                    const float* __restrict__ Wf, const float* __restrict__ bf,
                    float* __restrict__ out, int B)
{
    // per-wave double-buffered x staging: 2 rows x 128 floats x 2 buffers
    __shared__ float xbuf[4][512];

    const int tid  = threadIdx.x;
    const int wave = tid >> 6;
    const int lane = tid & 63;
    const int u    = lane & 31;   // branch-2 unit index (0..31)
    const int h    = lane >> 5;   // which k-half (0..1)

    // ---- preload weights into registers (per-lane slices) ----
    // w2r[j] = W2[u][64*h + j],  j = 0..63   (W2 is (32,128) row-major)
    float w2r[64];
    #pragma unroll
    for (int t = 0; t < 16; ++t) {
        const float4 v = *(const float4*)&W2[u * 128 + h * 64 + 4 * t];
        w2r[4*t+0] = v.x; w2r[4*t+1] = v.y; w2r[4*t+2] = v.z; w2r[4*t+3] = v.w;
    }
    // lane stores outputs d0=2*lane, d1=2*lane+1;   Wf is (128,64) row-major
    const int d0 = 2 * lane, d1 = 2 * lane + 1;
    float wf0[32], wf1[32];
    #pragma unroll
    for (int t = 0; t < 8; ++t) {
        const float4 a = *(const float4*)&Wf[d0 * 64 + 4 * t];
        wf0[4*t+0] = a.x; wf0[4*t+1] = a.y; wf0[4*t+2] = a.z; wf0[4*t+3] = a.w;
        const float4 b = *(const float4*)&Wf[d1 * 64 + 4 * t];
        wf1[4*t+0] = b.x; wf1[4*t+1] = b.y; wf1[4*t+2] = b.z; wf1[4*t+3] = b.w;
    }
    const float b2u = b2[u];
    const float bf0 = bf[d0], bf1 = bf[d1];

    const long long NP = (long long)(B >> 1);        // row pairs
    const int gw = blockIdx.x * 4 + wave;            // global wave id
    const int nw = gridDim.x * 4;                    // total waves

    long long pair = gw;
    float4 xv = make_float4(0.f, 0.f, 0.f, 0.f);
    if (pair < NP) xv = *(const float4*)&x[pair * 256 + lane * 4];

    int par = 0;
    for (; pair < NP; pair += nw, par ^= 1) {
        const float4 xc = xv;
        // prefetch next pair (1 KB per wave in flight)
        const long long nxt = pair + nw;
        if (nxt < NP) xv = *(const float4*)&x[nxt * 256 + lane * 4];

        // |x| partial sum; half h holds row h of the pair
        float sa = (fabsf(xc.x) + fabsf(xc.y)) + (fabsf(xc.z) + fabsf(xc.w));
        sa += __shfl_xor(sa, 1);
        sa += __shfl_xor(sa, 2);
        sa += __shfl_xor(sa, 4);
        sa += __shfl_xor(sa, 8);
        sa += __shfl_xor(sa, 16);   // every lane of a half: full |x| sum of its row

        // stage the pair's x into per-wave LDS (row p at [p*128, p*128+128))
        float* xw = &xbuf[wave][par * 0];           // single region per parity below
        xw = &xbuf[wave][0] + (par ? 256 : 0);
        *(float4*)&xw[lane * 4] = xc;
        lds_fence_wave();

        #pragma unroll
        for (int p = 0; p < 2; ++p) {
            // ---- stage 1: o2[u] = relu(x . W2[u] + b2[u]) ----
            float acc = 0.f;
            const float* xr = &xw[p * 128 + h * 64];
            #pragma unroll
            for (int t = 0; t < 16; ++t) {
                const float4 q = *(const float4*)&xr[4 * t];  // broadcast read
                acc = fmaf(q.x, w2r[4*t+0], acc);
                acc = fmaf(q.y, w2r[4*t+1], acc);
                acc = fmaf(q.z, w2r[4*t+2], acc);
                acc = fmaf(q.w, w2r[4*t+3], acc);
            }
            acc += __shfl_xor(acc, 32);                 // combine k-halves
            const float o2v = fmaxf(acc + b2u, 0.f);

            // ---- stage 2: out[d] = sum_u o2[u]*Wf[d][u] + bf[d] ----
            float a0 = bf0, a1 = bf1;
            #pragma unroll
            for (int uu = 0; uu < 32; ++uu) {
                const float tv = rl(o2v, uu);           // SGPR broadcast
                a0 = fmaf(tv, wf0[uu], a0);
                a1 = fmaf(tv, wf1[uu], a1);
            }

            // ---- rare branch-1 fixup (mean|x| > 1) ----
            const float sp = rl(sa, p * 32);            // row p's |x| sum (uniform)
            if (__builtin_expect(sp > THRESH_SUM, 0)) {
                // o1[lane] = relu(x . W1[lane] + b1[lane]), 64 units
                float od = 0.f;
                #pragma unroll 4
                for (int t = 0; t < 32; ++t) {
                    const float4 q  = *(const float4*)&xw[p * 128 + 4 * t];
                    const float4 wv = *(const float4*)&W1[lane * 128 + 4 * t];
                    od = fmaf(q.x, wv.x, od);
                    od = fmaf(q.y, wv.y, od);
                    od = fmaf(q.z, wv.z, od);
                    od = fmaf(q.w, wv.w, od);
                }
                const float o1v = fmaxf(od + b1[lane], 0.f);
                a0 = bf0; a1 = bf1;
                #pragma unroll 4
                for (int uu = 0; uu < 64; ++uu) {
                    const float tv = rl(o1v, uu);
                    a0 = fmaf(tv, Wf[d0 * 64 + uu], a0);
                    a1 = fmaf(tv, Wf[d1 * 64 + uu], a1);
                }
            }

            const long long row = pair * 2 + p;
            *(float2*)&out[row * 128 + d0] = make_float2(a0, a1);
        }
    }
}

extern "C" void kernel_launch(void* const* d_in, const int* in_sizes, int n_in,
                              void* d_out, int out_size, void* d_ws, size_t ws_size,
                              hipStream_t stream) {
    const float* x  = (const float*)d_in[0];
    const float* W1 = (const float*)d_in[1];
    const float* b1 = (const float*)d_in[2];
    const float* W2 = (const float*)d_in[3];
    const float* b2 = (const float*)d_in[4];
    const float* Wf = (const float*)d_in[5];
    const float* bf = (const float*)d_in[6];
    float* out = (float*)d_out;

    const int B = in_sizes[0] / 128;   // D = 128

    // 768 blocks x 256 threads = 3072 waves (3 waves/SIMD target occupancy)
    dim3 grid(768), block(256);
    hipLaunchKernelGGL(dyn_mlp_kernel, grid, block, 0, stream,
                       x, W1, b1, W2, b2, Wf, bf, out, B);
}